// Round 15
// baseline (255.564 us; speedup 1.0000x reference)
//
#include <hip/hip_runtime.h>

typedef __bf16 bf16;
typedef __bf16 bf16x8 __attribute__((ext_vector_type(8)));
typedef float  f32x4  __attribute__((ext_vector_type(4)));
typedef float  f32x16 __attribute__((ext_vector_type(16)));
typedef int    i32x4  __attribute__((ext_vector_type(4)));
typedef int    i32x16 __attribute__((ext_vector_type(16)));
typedef signed char i8;

#define OC_N   4096
#define IC_K   4096
#define TOKENS 4096
#define KC     256   // outlier K padded to 8x32

// ---------------------------------------------------------------------------
// Fused prep, one block per row r (TOKENS == OC_N == 4096).  UNCHANGED (v5).
// ---------------------------------------------------------------------------
__global__ __launch_bounds__(256) void prep_kernel(
    const float* __restrict__ w, const float* __restrict__ x,
    const float* __restrict__ ow, const int* __restrict__ idx,
    i8* __restrict__ wsgn, i8* __restrict__ xq,
    bf16* __restrict__ xo, bf16* __restrict__ wcorr,
    float* __restrict__ scale_arr, float* __restrict__ sx_arr, int n_out)
{
    __shared__ float red[8];
    const int row = blockIdx.x;
    const int t = threadIdx.x;
    const int lane = t & 63, wv = t >> 6;

    const float4* wr = (const float4*)(w + (size_t)row * IC_K);
    const float4* xr = (const float4*)(x + (size_t)row * IC_K);
    float4 v[4], u[4];
#pragma unroll
    for (int i = 0; i < 4; i++) v[i] = wr[i * 256 + t];
#pragma unroll
    for (int i = 0; i < 4; i++) u[i] = xr[i * 256 + t];

    float xg = 0.f, wg = 0.f, og = 0.f;
    if (t < n_out) {
        const int colg = idx[t];
        xg = x[(size_t)row * IC_K + colg];
        wg = w[(size_t)row * IC_K + colg];
        og = ow[(size_t)row * n_out + t];
    }

    float s = 0.f;
#pragma unroll
    for (int i = 0; i < 4; i++)
        s += v[i].x + v[i].y + v[i].z + v[i].w;
    for (int o = 32; o > 0; o >>= 1) s += __shfl_down(s, o, 64);
    if (lane == 0) red[wv] = s;
    __syncthreads();
    const float mean = (red[0] + red[1] + red[2] + red[3]) * (1.f / IC_K);

    float sa = 0.f;
#pragma unroll
    for (int i = 0; i < 4; i++) {
        sa += fabsf(v[i].x - mean) + fabsf(v[i].y - mean) +
              fabsf(v[i].z - mean) + fabsf(v[i].w - mean);
    }
    for (int o = 32; o > 0; o >>= 1) sa += __shfl_down(sa, o, 64);
    if (lane == 0) red[4 + wv] = sa;
    __syncthreads();
    const float scale = (red[4] + red[5] + red[6] + red[7]) * (1.f / IC_K);

    i8* srow = wsgn + (size_t)row * IC_K;
#pragma unroll
    for (int i = 0; i < 4; i++) {
        float c[4] = { v[i].x - mean, v[i].y - mean, v[i].z - mean, v[i].w - mean };
        char4 q;
        q.x = (i8)((c[0] > 0.f) - (c[0] < 0.f));
        q.y = (i8)((c[1] > 0.f) - (c[1] < 0.f));
        q.z = (i8)((c[2] > 0.f) - (c[2] < 0.f));
        q.w = (i8)((c[3] > 0.f) - (c[3] < 0.f));
        *(char4*)(srow + (size_t)(i * 256 + t) * 4) = q;
    }

    float mx = 0.f;
#pragma unroll
    for (int i = 0; i < 4; i++)
        mx = fmaxf(mx, fmaxf(fmaxf(fabsf(u[i].x), fabsf(u[i].y)),
                             fmaxf(fabsf(u[i].z), fabsf(u[i].w))));
    for (int o = 32; o > 0; o >>= 1) mx = fmaxf(mx, __shfl_down(mx, o, 64));
    if (lane == 0) red[wv] = mx;
    __syncthreads();
    const float maxv = fmaxf(fmaxf(red[0], red[1]), fmaxf(red[2], red[3]));
    const float inv = maxv > 0.f ? 127.f / maxv : 0.f;
    const float sxv = maxv > 0.f ? maxv * (1.f / 127.f) : 1.f;

    i8* xrow = xq + (size_t)row * IC_K;
#pragma unroll
    for (int i = 0; i < 4; i++) {
        char4 q;
        q.x = (i8)(int)rintf(u[i].x * inv);
        q.y = (i8)(int)rintf(u[i].y * inv);
        q.z = (i8)(int)rintf(u[i].z * inv);
        q.w = (i8)(int)rintf(u[i].w * inv);
        *(char4*)(xrow + (size_t)(i * 256 + t) * 4) = q;
    }
    if (t == 0) { scale_arr[row] = scale; sx_arr[row] = sxv; }

    if (t < n_out) {
        xo[(size_t)row * KC + t] = (bf16)xg;
        const float wc_ = wg - mean;
        const float sg = (wc_ > 0.f) ? 1.f : ((wc_ < 0.f) ? -1.f : 0.f);
        wcorr[(size_t)row * KC + t] = (bf16)(og - scale * sg);
    } else if (t < KC) {
        xo[(size_t)row * KC + t] = (bf16)0.f;
        wcorr[(size_t)row * KC + t] = (bf16)0.f;
    }
}

// ---------------------------------------------------------------------------
// GEMM v10: v5 with HALVED PHASE COUNT via depth-2 SUPER-CHUNK ring.
// v5 (3x confirmed): gemm 85.8-87.2us, wall ~2420cy/phase vs LDS pipe
// ~1790cy.  Residual slack hypothesis: fixed per-phase cost (barrier ~90cy
// [v4 A/B] + post-barrier ds_read->MFMA bubble ~150cy [v5 A/B]) x 64
// phases.  v10 merges 2 chunks per barrier interval:
//   super-slot = A 32KB + B 32KB; ring depth 2 = 128KB LDS.
//   interval s: VMCNT(0); BAR; reads(2s); stage_super(s+1); mfma(2s);
//               reads(2s+1); mfma(2s+1)     [SCHED0-pinned halves]
// VMCNT(0) is FREE in steady state: stage_super(s) was issued one full
// interval (~4800cy >> 900cy HBM) earlier.  Ledger trivial (no counted
// tails).  WAR: write slot (s+1)&1 != read slot s&1; previous occupant
// (super s-1) fully read before the interval-s barrier.  RAW: per-wave
// vmcnt(0) drain + BAR publishes super s to all waves.
// Register-neutral: ONE 48-reg frag set, halves pinned by SCHED0 (v8's
// spill trap avoided; VGPR must stay 128 - check counter).
// Accumulation order identical to v5 -> absmax bit-identical 0.0546875.
// PRE-COMMITTED: if gemm >= 85us, slack is proportional -> ROOFLINE.
// ---------------------------------------------------------------------------
__device__ __forceinline__ void gload16(const void* g, void* l)
{
    __builtin_amdgcn_global_load_lds(
        (const __attribute__((address_space(1))) void*)g,
        (__attribute__((address_space(3))) void*)l, 16, 0, 0);
}

#define VMCNT(n) asm volatile("s_waitcnt vmcnt(" #n ")" ::: "memory")
#define SCHED0   __builtin_amdgcn_sched_barrier(0)
#define BAR      __builtin_amdgcn_s_barrier()

__global__ __launch_bounds__(512, 2) void gemm_kernel(
    const i8* __restrict__ A, const i8* __restrict__ B,
    const bf16* __restrict__ Axo, const bf16* __restrict__ Bwc,
    const float* __restrict__ sx, const float* __restrict__ scale,
    const float* __restrict__ bias, float* __restrict__ C)
{
    constexpr int K = IC_K, N = OC_N;
    __shared__ __align__(16) i8 ring[2][2][32768];   // 128 KB

    const int tid  = threadIdx.x;
    const int lane = tid & 63;
    const int wave = tid >> 6;
    const int wm = wave >> 2, wn = wave & 3;          // 2 (M) x 4 (N) waves
    const int m32 = lane & 31, kg = lane >> 5;

    // XCD-aware 4x8 rectangle per XCD (bijective; 256 blocks, 8 XCDs)
    const int bid = blockIdx.x;
    const int xcd = bid & 7, tix = bid >> 3;
    const int bm = (xcd >> 1) * 4 + (tix & 3);
    const int bn = (xcd & 1) * 8 + (tix >> 2);

    // ---- staging map: LDS quad Q = tid (+512) -> (row, swizzled qk) ----
    const int Q0 = tid, Q1 = 512 + tid;
    const int r0 = Q0 >> 2, r1 = Q1 >> 2;
    const int q0 = (Q0 & 3) ^ ((r0 >> 1) & 3);
    const int q1 = (Q1 & 3) ^ ((r1 >> 1) & 3);
    const int d0 = Q0 * 16, d1 = Q1 * 16;

    const i8* gA0 = A + (size_t)(bm * 256 + r0) * K + q0 * 16;
    const i8* gA1 = A + (size_t)(bm * 256 + r1) * K + q1 * 16;
    const i8* gB0 = B + (size_t)(bn * 256 + r0) * K + q0 * 16;
    const i8* gB1 = B + (size_t)(bn * 256 + r1) * K + q1 * 16;

    // stage chunks 2s, 2s+1 into super-slot s&1 (8 gload_lds)
    auto stage_super = [&](int s) {
        i8* aslot = &ring[s & 1][0][0];
        i8* bslot = &ring[s & 1][1][0];
#pragma unroll
        for (int h = 0; h < 2; ++h) {
            const int ko = (2 * s + h) * 64;
            gload16(gA0 + ko, aslot + h * 16384 + d0);
            gload16(gA1 + ko, aslot + h * 16384 + d1);
            gload16(gB0 + ko, bslot + h * 16384 + d0);
            gload16(gB1 + ko, bslot + h * 16384 + d1);
        }
    };

    // ---- per-lane ds_read byte offsets (shared by i8 and bf16 loops) ----
    int offA[4][2], offB[2][2];
#pragma unroll
    for (int mi = 0; mi < 4; ++mi) {
        const int r = wm * 128 + mi * 32 + m32;
#pragma unroll
        for (int ks = 0; ks < 2; ++ks)
            offA[mi][ks] = r * 64 + ((ks * 2 + kg) ^ ((r >> 1) & 3)) * 16;
    }
#pragma unroll
    for (int ni = 0; ni < 2; ++ni) {
        const int r = wn * 64 + ni * 32 + m32;
#pragma unroll
        for (int ks = 0; ks < 2; ++ks)
            offB[ni][ks] = r * 64 + ((ks * 2 + kg) ^ ((r >> 1) & 3)) * 16;
    }

    i32x16 acc[4][2] = {};

    auto reads_i8 = [&](int s, int h, i32x4 (&af)[4][2], i32x4 (&bfr)[2][2]) {
        const i8* sA = &ring[s & 1][0][h * 16384];
        const i8* sB = &ring[s & 1][1][h * 16384];
#pragma unroll
        for (int mi = 0; mi < 4; ++mi)
#pragma unroll
            for (int ks = 0; ks < 2; ++ks)
                af[mi][ks] = *(const i32x4*)(sA + offA[mi][ks]);
#pragma unroll
        for (int ni = 0; ni < 2; ++ni)
#pragma unroll
            for (int ks = 0; ks < 2; ++ks)
                bfr[ni][ks] = *(const i32x4*)(sB + offB[ni][ks]);
    };
    auto mfma_i8 = [&](i32x4 (&af)[4][2], i32x4 (&bfr)[2][2]) {
        __builtin_amdgcn_s_setprio(1);
#pragma unroll
        for (int ks = 0; ks < 2; ++ks)
#pragma unroll
            for (int mi = 0; mi < 4; ++mi)
#pragma unroll
                for (int ni = 0; ni < 2; ++ni)
                    acc[mi][ni] = __builtin_amdgcn_mfma_i32_32x32x32_i8(
                        af[mi][ks], bfr[ni][ks], acc[mi][ni], 0, 0, 0);
        __builtin_amdgcn_s_setprio(0);
    };

    // ---- main i8 loop: 32 super-intervals (64 chunks), depth-2 ring ----
    stage_super(0);
    for (int s = 0; s < 31; ++s) {
        VMCNT(0); BAR; SCHED0;
        i32x4 af[4][2], bfr[2][2];
        reads_i8(s, 0, af, bfr);
        SCHED0;
        stage_super(s + 1);
        SCHED0;
        mfma_i8(af, bfr);
        SCHED0;
        reads_i8(s, 1, af, bfr);
        SCHED0;
        mfma_i8(af, bfr);
    }
    {   // interval 31: chunks 62,63 — nothing left to stage
        VMCNT(0); BAR; SCHED0;
        i32x4 af[4][2], bfr[2][2];
        reads_i8(31, 0, af, bfr); SCHED0; mfma_i8(af, bfr);
        SCHED0;
        reads_i8(31, 1, af, bfr); SCHED0; mfma_i8(af, bfr);
    }

    // ---- i32 -> f32 scaling (32x32 C layout: row=(r&3)+8*(r>>2)+4*kg) ----
    const int rbase = bm * 256 + wm * 128 + 4 * kg;
    const int cbase = bn * 256 + wn * 64 + m32;
    float scl2[2], bv2[2];
#pragma unroll
    for (int ni = 0; ni < 2; ++ni) {
        scl2[ni] = scale[cbase + ni * 32];
        bv2[ni]  = bias[cbase + ni * 32];
    }
    f32x16 facc[4][2];
#pragma unroll
    for (int mi = 0; mi < 4; ++mi)
#pragma unroll
        for (int r = 0; r < 16; ++r) {
            const float sxv = sx[rbase + mi * 32 + (r & 3) + 8 * (r >> 2)];
#pragma unroll
            for (int ni = 0; ni < 2; ++ni)
                facc[mi][ni][r] = (float)acc[mi][ni][r] * sxv * scl2[ni];
        }
    // drain scalar loads; barrier publishes end of i8-phase LDS reads
    asm volatile("s_waitcnt vmcnt(0)" ::: "memory");
    BAR;

    // ---- bf16 correction: 8 chunks (K=32) = 4 super-intervals ----
    const i8* cA0 = (const i8*)Axo + (size_t)(bm * 256 + r0) * (KC * 2) + q0 * 16;
    const i8* cA1 = (const i8*)Axo + (size_t)(bm * 256 + r1) * (KC * 2) + q1 * 16;
    const i8* cB0 = (const i8*)Bwc + (size_t)(bn * 256 + r0) * (KC * 2) + q0 * 16;
    const i8* cB1 = (const i8*)Bwc + (size_t)(bn * 256 + r1) * (KC * 2) + q1 * 16;
    auto stagec_super = [&](int s) {
        i8* aslot = &ring[s & 1][0][0];
        i8* bslot = &ring[s & 1][1][0];
#pragma unroll
        for (int h = 0; h < 2; ++h) {
            const int ko = (2 * s + h) * 64;
            gload16(cA0 + ko, aslot + h * 16384 + d0);
            gload16(cA1 + ko, aslot + h * 16384 + d1);
            gload16(cB0 + ko, bslot + h * 16384 + d0);
            gload16(cB1 + ko, bslot + h * 16384 + d1);
        }
    };
    auto reads_bf = [&](int s, int h, bf16x8 (&af)[4][2], bf16x8 (&bfr)[2][2]) {
        const i8* sA = &ring[s & 1][0][h * 16384];
        const i8* sB = &ring[s & 1][1][h * 16384];
#pragma unroll
        for (int mi = 0; mi < 4; ++mi)
#pragma unroll
            for (int ks = 0; ks < 2; ++ks)
                af[mi][ks] = *(const bf16x8*)(sA + offA[mi][ks]);
#pragma unroll
        for (int ni = 0; ni < 2; ++ni)
#pragma unroll
            for (int ks = 0; ks < 2; ++ks)
                bfr[ni][ks] = *(const bf16x8*)(sB + offB[ni][ks]);
    };
    auto mfma_bf = [&](bf16x8 (&af)[4][2], bf16x8 (&bfr)[2][2]) {
        __builtin_amdgcn_s_setprio(1);
#pragma unroll
        for (int ks = 0; ks < 2; ++ks)
#pragma unroll
            for (int mi = 0; mi < 4; ++mi)
#pragma unroll
                for (int ni = 0; ni < 2; ++ni)
                    facc[mi][ni] = __builtin_amdgcn_mfma_f32_32x32x16_bf16(
                        af[mi][ks], bfr[ni][ks], facc[mi][ni], 0, 0, 0);
        __builtin_amdgcn_s_setprio(0);
    };

    stagec_super(0);
    for (int s = 0; s < 3; ++s) {
        VMCNT(0); BAR; SCHED0;
        bf16x8 af[4][2], bfr[2][2];
        reads_bf(s, 0, af, bfr);
        SCHED0;
        stagec_super(s + 1);
        SCHED0;
        mfma_bf(af, bfr);
        SCHED0;
        reads_bf(s, 1, af, bfr);
        SCHED0;
        mfma_bf(af, bfr);
    }
    {
        VMCNT(0); BAR; SCHED0;
        bf16x8 af[4][2], bfr[2][2];
        reads_bf(3, 0, af, bfr); SCHED0; mfma_bf(af, bfr);
        SCHED0;
        reads_bf(3, 1, af, bfr); SCHED0; mfma_bf(af, bfr);
    }

    // ---- epilogue: + bias, store ----
#pragma unroll
    for (int mi = 0; mi < 4; ++mi)
#pragma unroll
        for (int r = 0; r < 16; ++r) {
            const int row = rbase + mi * 32 + (r & 3) + 8 * (r >> 2);
#pragma unroll
            for (int ni = 0; ni < 2; ++ni)
                C[(size_t)row * N + cbase + ni * 32] = facc[mi][ni][r] + bv2[ni];
        }
}

// ---------------------------------------------------------------------------
extern "C" void kernel_launch(void* const* d_in, const int* in_sizes, int n_in,
                              void* d_out, int out_size, void* d_ws, size_t ws_size,
                              hipStream_t stream)
{
    const float* x    = (const float*)d_in[0];
    const float* w    = (const float*)d_in[1];
    const float* bias = (const float*)d_in[2];
    const float* ow   = (const float*)d_in[3];
    const int*   idx  = (const int*)d_in[4];
    const int    n_out = in_sizes[4];
    float* out = (float*)d_out;

    char* ws = (char*)d_ws;
    i8*    xq    = (i8*)ws;                                   // 16 MB
    i8*    wsgn  = (i8*)(ws + (size_t)16 * 1024 * 1024);      // 16 MB
    bf16*  xo    = (bf16*)(ws + (size_t)32 * 1024 * 1024);    // 2 MB
    bf16*  wcorr = (bf16*)(ws + (size_t)34 * 1024 * 1024);    // 2 MB
    float* sx    = (float*)(ws + (size_t)36 * 1024 * 1024);   // 16 KB
    float* scl   = (float*)(ws + (size_t)36 * 1024 * 1024 + 16 * 1024); // 16 KB

    hipLaunchKernelGGL(prep_kernel, dim3(OC_N), dim3(256), 0, stream,
                       w, x, ow, idx, wsgn, xq, xo, wcorr, scl, sx, n_out);
    hipLaunchKernelGGL(gemm_kernel, dim3(256), dim3(512), 0, stream,
                       xq, wsgn, xo, wcorr, sx, scl, bias, out);
}

// Round 16
// 253.134 us; speedup vs baseline: 1.0096x; 1.0096x over previous
//
#include <hip/hip_runtime.h>

typedef __bf16 bf16;
typedef __bf16 bf16x8 __attribute__((ext_vector_type(8)));
typedef float  f32x4  __attribute__((ext_vector_type(4)));
typedef float  f32x16 __attribute__((ext_vector_type(16)));
typedef int    i32x4  __attribute__((ext_vector_type(4)));
typedef int    i32x16 __attribute__((ext_vector_type(16)));
typedef signed char i8;

#define OC_N   4096
#define IC_K   4096
#define TOKENS 4096
#define KC     256   // outlier K padded to 8x32

// ---------------------------------------------------------------------------
// Fused prep, one block per row r (TOKENS == OC_N == 4096).  (v5 version)
// ---------------------------------------------------------------------------
__global__ __launch_bounds__(256) void prep_kernel(
    const float* __restrict__ w, const float* __restrict__ x,
    const float* __restrict__ ow, const int* __restrict__ idx,
    i8* __restrict__ wsgn, i8* __restrict__ xq,
    bf16* __restrict__ xo, bf16* __restrict__ wcorr,
    float* __restrict__ scale_arr, float* __restrict__ sx_arr, int n_out)
{
    __shared__ float red[8];
    const int row = blockIdx.x;
    const int t = threadIdx.x;
    const int lane = t & 63, wv = t >> 6;

    const float4* wr = (const float4*)(w + (size_t)row * IC_K);
    const float4* xr = (const float4*)(x + (size_t)row * IC_K);
    float4 v[4], u[4];
#pragma unroll
    for (int i = 0; i < 4; i++) v[i] = wr[i * 256 + t];
#pragma unroll
    for (int i = 0; i < 4; i++) u[i] = xr[i * 256 + t];

    float xg = 0.f, wg = 0.f, og = 0.f;
    if (t < n_out) {
        const int colg = idx[t];
        xg = x[(size_t)row * IC_K + colg];
        wg = w[(size_t)row * IC_K + colg];
        og = ow[(size_t)row * n_out + t];
    }

    float s = 0.f;
#pragma unroll
    for (int i = 0; i < 4; i++)
        s += v[i].x + v[i].y + v[i].z + v[i].w;
    for (int o = 32; o > 0; o >>= 1) s += __shfl_down(s, o, 64);
    if (lane == 0) red[wv] = s;
    __syncthreads();
    const float mean = (red[0] + red[1] + red[2] + red[3]) * (1.f / IC_K);

    float sa = 0.f;
#pragma unroll
    for (int i = 0; i < 4; i++) {
        sa += fabsf(v[i].x - mean) + fabsf(v[i].y - mean) +
              fabsf(v[i].z - mean) + fabsf(v[i].w - mean);
    }
    for (int o = 32; o > 0; o >>= 1) sa += __shfl_down(sa, o, 64);
    if (lane == 0) red[4 + wv] = sa;
    __syncthreads();
    const float scale = (red[4] + red[5] + red[6] + red[7]) * (1.f / IC_K);

    i8* srow = wsgn + (size_t)row * IC_K;
#pragma unroll
    for (int i = 0; i < 4; i++) {
        float c[4] = { v[i].x - mean, v[i].y - mean, v[i].z - mean, v[i].w - mean };
        char4 q;
        q.x = (i8)((c[0] > 0.f) - (c[0] < 0.f));
        q.y = (i8)((c[1] > 0.f) - (c[1] < 0.f));
        q.z = (i8)((c[2] > 0.f) - (c[2] < 0.f));
        q.w = (i8)((c[3] > 0.f) - (c[3] < 0.f));
        *(char4*)(srow + (size_t)(i * 256 + t) * 4) = q;
    }

    float mx = 0.f;
#pragma unroll
    for (int i = 0; i < 4; i++)
        mx = fmaxf(mx, fmaxf(fmaxf(fabsf(u[i].x), fabsf(u[i].y)),
                             fmaxf(fabsf(u[i].z), fabsf(u[i].w))));
    for (int o = 32; o > 0; o >>= 1) mx = fmaxf(mx, __shfl_down(mx, o, 64));
    if (lane == 0) red[wv] = mx;
    __syncthreads();
    const float maxv = fmaxf(fmaxf(red[0], red[1]), fmaxf(red[2], red[3]));
    const float inv = maxv > 0.f ? 127.f / maxv : 0.f;
    const float sxv = maxv > 0.f ? maxv * (1.f / 127.f) : 1.f;

    i8* xrow = xq + (size_t)row * IC_K;
#pragma unroll
    for (int i = 0; i < 4; i++) {
        char4 q;
        q.x = (i8)(int)rintf(u[i].x * inv);
        q.y = (i8)(int)rintf(u[i].y * inv);
        q.z = (i8)(int)rintf(u[i].z * inv);
        q.w = (i8)(int)rintf(u[i].w * inv);
        *(char4*)(xrow + (size_t)(i * 256 + t) * 4) = q;
    }
    if (t == 0) { scale_arr[row] = scale; sx_arr[row] = sxv; }

    if (t < n_out) {
        xo[(size_t)row * KC + t] = (bf16)xg;
        const float wc_ = wg - mean;
        const float sg = (wc_ > 0.f) ? 1.f : ((wc_ < 0.f) ? -1.f : 0.f);
        wcorr[(size_t)row * KC + t] = (bf16)(og - scale * sg);
    } else if (t < KC) {
        xo[(size_t)row * KC + t] = (bf16)0.f;
        wcorr[(size_t)row * KC + t] = (bf16)0.f;
    }
}

// ---------------------------------------------------------------------------
// GEMM FINAL == v5 (measured best, 3x: gemm 85.8-87.2us, total 251.95us).
// COMPLETE STRUCTURAL BOX (every wall probed with counters):
//  - v6 2-bit-packed B: FETCH 56->31MB but +80 VALU/phase on MFMA critical
//    path -> 98.5us.  Traffic cuts that add critical-path VALU regress.
//  - v8 reg-pipelined frags: 256-reg/wave cap at 2-wave/SIMD is HARD ->
//    spills (WRITE 66->85MB) -> 98us.
//  - v10 halved phase count (depth-2 super-chunk, VMCNT(0)/interval):
//    99us.  Counted-vmcnt continuous flight (12-16 loads) beats burst+
//    drain (8 loads) — Little's law; slack is PROPORTIONAL to LDS work,
//    not fixed-per-phase.
//  - conflicts pinned at exactly 7,077,888 across v2-v5 AND v10
//    (= 96 b128-reads x 4cy x 72 phases x 256 CU): read-pattern tax.
//  - pipes/phase: MFMA 1170cy, LDS ~1790cy (binding), wall ~2420cy;
//    residual = cross-pipe dependency slack, irreducible at 2 waves/SIMD
//    (LDS-bound occupancy) with zero spare registers (128V+128A = cap).
// Structure: 256x256 tile, 8 waves (2Mx4N), depth-5 LDS ring (160KB),
// ONE barrier/phase, reads-first body, XCD-aware 4x8 tiling, counted
// vmcnt (never 0 in steady state), setprio around MFMA clusters.
// ---------------------------------------------------------------------------
__device__ __forceinline__ void gload16(const void* g, void* l)
{
    __builtin_amdgcn_global_load_lds(
        (const __attribute__((address_space(1))) void*)g,
        (__attribute__((address_space(3))) void*)l, 16, 0, 0);
}

#define VMCNT(n) asm volatile("s_waitcnt vmcnt(" #n ")" ::: "memory")
#define SCHED0   __builtin_amdgcn_sched_barrier(0)
#define BAR      __builtin_amdgcn_s_barrier()

__global__ __launch_bounds__(512, 2) void gemm_kernel(
    const i8* __restrict__ A, const i8* __restrict__ B,
    const bf16* __restrict__ Axo, const bf16* __restrict__ Bwc,
    const float* __restrict__ sx, const float* __restrict__ scale,
    const float* __restrict__ bias, float* __restrict__ C)
{
    constexpr int K = IC_K, N = OC_N;
    __shared__ __align__(16) i8 ring[5][2][16384];   // 160 KB (full pool)

    const int tid  = threadIdx.x;
    const int lane = tid & 63;
    const int wave = tid >> 6;
    const int wm = wave >> 2, wn = wave & 3;          // 2 (M) x 4 (N) waves
    const int m32 = lane & 31, kg = lane >> 5;

    // XCD-aware 4x8 rectangle per XCD (bijective; 256 blocks, 8 XCDs)
    const int bid = blockIdx.x;
    const int xcd = bid & 7, tix = bid >> 3;          // 32 tiles per XCD
    const int bm = (xcd >> 1) * 4 + (tix & 3);        // 16 values
    const int bn = (xcd & 1) * 8 + (tix >> 2);        // 16 values

    // ---- staging map: LDS quad Q = tid (+512) -> (row, swizzled qk) ----
    const int Q0 = tid, Q1 = 512 + tid;
    const int r0 = Q0 >> 2, r1 = Q1 >> 2;
    const int q0 = (Q0 & 3) ^ ((r0 >> 1) & 3);
    const int q1 = (Q1 & 3) ^ ((r1 >> 1) & 3);
    const int d0 = Q0 * 16, d1 = Q1 * 16;

    const i8* gA0 = A + (size_t)(bm * 256 + r0) * K + q0 * 16;
    const i8* gA1 = A + (size_t)(bm * 256 + r1) * K + q1 * 16;
    const i8* gB0 = B + (size_t)(bn * 256 + r0) * K + q0 * 16;
    const i8* gB1 = B + (size_t)(bn * 256 + r1) * K + q1 * 16;

    auto stage = [&](int c) {
        i8* bs = &ring[c % 5][0][0];
        const int ko = c * 64;
        gload16(gA0 + ko, bs + d0);
        gload16(gA1 + ko, bs + d1);
        gload16(gB0 + ko, bs + 16384 + d0);
        gload16(gB1 + ko, bs + 16384 + d1);
    };

    // ---- per-lane ds_read byte offsets (shared by i8 and bf16 loops) ----
    int offA[4][2], offB[2][2];
#pragma unroll
    for (int mi = 0; mi < 4; ++mi) {
        const int r = wm * 128 + mi * 32 + m32;
#pragma unroll
        for (int ks = 0; ks < 2; ++ks)
            offA[mi][ks] = r * 64 + ((ks * 2 + kg) ^ ((r >> 1) & 3)) * 16;
    }
#pragma unroll
    for (int ni = 0; ni < 2; ++ni) {
        const int r = wn * 64 + ni * 32 + m32;
#pragma unroll
        for (int ks = 0; ks < 2; ++ks)
            offB[ni][ks] = r * 64 + ((ks * 2 + kg) ^ ((r >> 1) & 3)) * 16;
    }

    i32x16 acc[4][2] = {};

    auto reads_i8 = [&](int c, i32x4 (&af)[4][2], i32x4 (&bfr)[2][2]) {
        const i8* sA = &ring[c % 5][0][0];
        const i8* sB = sA + 16384;
#pragma unroll
        for (int mi = 0; mi < 4; ++mi)
#pragma unroll
            for (int ks = 0; ks < 2; ++ks)
                af[mi][ks] = *(const i32x4*)(sA + offA[mi][ks]);
#pragma unroll
        for (int ni = 0; ni < 2; ++ni)
#pragma unroll
            for (int ks = 0; ks < 2; ++ks)
                bfr[ni][ks] = *(const i32x4*)(sB + offB[ni][ks]);
    };
    auto mfma_i8 = [&](i32x4 (&af)[4][2], i32x4 (&bfr)[2][2]) {
        __builtin_amdgcn_s_setprio(1);
#pragma unroll
        for (int ks = 0; ks < 2; ++ks)
#pragma unroll
            for (int mi = 0; mi < 4; ++mi)
#pragma unroll
                for (int ni = 0; ni < 2; ++ni)
                    acc[mi][ni] = __builtin_amdgcn_mfma_i32_32x32x32_i8(
                        af[mi][ks], bfr[ni][ks], acc[mi][ni], 0, 0, 0);
        __builtin_amdgcn_s_setprio(0);
    };

    // ---- main i8 loop: 64 chunks, depth 5, one barrier, reads-first ----
    stage(0); stage(1); stage(2); stage(3);
#pragma unroll 5
    for (int c = 0; c < 60; ++c) {
        VMCNT(12); BAR; SCHED0;
        i32x4 af[4][2], bfr[2][2];
        reads_i8(c, af, bfr);
        SCHED0;
        stage(c + 4);
        SCHED0;
        mfma_i8(af, bfr);
    }
    {
        i32x4 af[4][2], bfr[2][2];
        VMCNT(12); BAR; SCHED0; reads_i8(60, af, bfr); SCHED0; mfma_i8(af, bfr);
        VMCNT(8);  BAR; SCHED0; reads_i8(61, af, bfr); SCHED0; mfma_i8(af, bfr);
        VMCNT(4);  BAR; SCHED0; reads_i8(62, af, bfr); SCHED0; mfma_i8(af, bfr);
        VMCNT(0);  BAR; SCHED0; reads_i8(63, af, bfr); SCHED0; mfma_i8(af, bfr);
    }

    // ---- i32 -> f32 scaling (32x32 C layout: row=(r&3)+8*(r>>2)+4*kg) ----
    const int rbase = bm * 256 + wm * 128 + 4 * kg;
    const int cbase = bn * 256 + wn * 64 + m32;
    float scl2[2], bv2[2];
#pragma unroll
    for (int ni = 0; ni < 2; ++ni) {
        scl2[ni] = scale[cbase + ni * 32];
        bv2[ni]  = bias[cbase + ni * 32];
    }
    f32x16 facc[4][2];
#pragma unroll
    for (int mi = 0; mi < 4; ++mi)
#pragma unroll
        for (int r = 0; r < 16; ++r) {
            const float sxv = sx[rbase + mi * 32 + (r & 3) + 8 * (r >> 2)];
#pragma unroll
            for (int ni = 0; ni < 2; ++ni)
                facc[mi][ni][r] = (float)acc[mi][ni][r] * sxv * scl2[ni];
        }
    // drain sx/scale/bias loads (exact vmcnt counts for corr loop) and
    // barrier: all waves' i8-phase LDS reads are done before slot reuse.
    asm volatile("s_waitcnt vmcnt(0)" ::: "memory");
    BAR;

    // ---- bf16 correction: 8 chunks of K=32 over KC=256, same schedule ----
    const i8* cA0 = (const i8*)Axo + (size_t)(bm * 256 + r0) * (KC * 2) + q0 * 16;
    const i8* cA1 = (const i8*)Axo + (size_t)(bm * 256 + r1) * (KC * 2) + q1 * 16;
    const i8* cB0 = (const i8*)Bwc + (size_t)(bn * 256 + r0) * (KC * 2) + q0 * 16;
    const i8* cB1 = (const i8*)Bwc + (size_t)(bn * 256 + r1) * (KC * 2) + q1 * 16;
    auto stagec = [&](int c) {
        i8* bs = &ring[c % 5][0][0];
        const int ko = c * 64;
        gload16(cA0 + ko, bs + d0);
        gload16(cA1 + ko, bs + d1);
        gload16(cB0 + ko, bs + 16384 + d0);
        gload16(cB1 + ko, bs + 16384 + d1);
    };
    auto reads_bf = [&](int c, bf16x8 (&af)[4][2], bf16x8 (&bfr)[2][2]) {
        const i8* sA = &ring[c % 5][0][0];
        const i8* sB = sA + 16384;
#pragma unroll
        for (int mi = 0; mi < 4; ++mi)
#pragma unroll
            for (int ks = 0; ks < 2; ++ks)
                af[mi][ks] = *(const bf16x8*)(sA + offA[mi][ks]);
#pragma unroll
        for (int ni = 0; ni < 2; ++ni)
#pragma unroll
            for (int ks = 0; ks < 2; ++ks)
                bfr[ni][ks] = *(const bf16x8*)(sB + offB[ni][ks]);
    };
    auto mfma_bf = [&](bf16x8 (&af)[4][2], bf16x8 (&bfr)[2][2]) {
        __builtin_amdgcn_s_setprio(1);
#pragma unroll
        for (int ks = 0; ks < 2; ++ks)
#pragma unroll
            for (int mi = 0; mi < 4; ++mi)
#pragma unroll
                for (int ni = 0; ni < 2; ++ni)
                    facc[mi][ni] = __builtin_amdgcn_mfma_f32_32x32x16_bf16(
                        af[mi][ks], bfr[ni][ks], facc[mi][ni], 0, 0, 0);
        __builtin_amdgcn_s_setprio(0);
    };

    stagec(0); stagec(1); stagec(2);
#pragma unroll
    for (int c = 0; c < 5; ++c) {
        VMCNT(8); BAR; SCHED0;
        bf16x8 af[4][2], bfr[2][2];
        reads_bf(c, af, bfr);
        SCHED0;
        stagec(c + 3);
        SCHED0;
        mfma_bf(af, bfr);
    }
    {
        bf16x8 af[4][2], bfr[2][2];
        VMCNT(8); BAR; SCHED0; reads_bf(5, af, bfr); SCHED0; mfma_bf(af, bfr);
        VMCNT(4); BAR; SCHED0; reads_bf(6, af, bfr); SCHED0; mfma_bf(af, bfr);
        VMCNT(0); BAR; SCHED0; reads_bf(7, af, bfr); SCHED0; mfma_bf(af, bfr);
    }

    // ---- epilogue: + bias, store ----
#pragma unroll
    for (int mi = 0; mi < 4; ++mi)
#pragma unroll
        for (int r = 0; r < 16; ++r) {
            const int row = rbase + mi * 32 + (r & 3) + 8 * (r >> 2);
#pragma unroll
            for (int ni = 0; ni < 2; ++ni)
                C[(size_t)row * N + cbase + ni * 32] = facc[mi][ni][r] + bv2[ni];
        }
}

// ---------------------------------------------------------------------------
extern "C" void kernel_launch(void* const* d_in, const int* in_sizes, int n_in,
                              void* d_out, int out_size, void* d_ws, size_t ws_size,
                              hipStream_t stream)
{
    const float* x    = (const float*)d_in[0];
    const float* w    = (const float*)d_in[1];
    const float* bias = (const float*)d_in[2];
    const float* ow   = (const float*)d_in[3];
    const int*   idx  = (const int*)d_in[4];
    const int    n_out = in_sizes[4];
    float* out = (float*)d_out;

    char* ws = (char*)d_ws;
    i8*    xq    = (i8*)ws;                                   // 16 MB
    i8*    wsgn  = (i8*)(ws + (size_t)16 * 1024 * 1024);      // 16 MB
    bf16*  xo    = (bf16*)(ws + (size_t)32 * 1024 * 1024);    // 2 MB
    bf16*  wcorr = (bf16*)(ws + (size_t)34 * 1024 * 1024);    // 2 MB
    float* sx    = (float*)(ws + (size_t)36 * 1024 * 1024);   // 16 KB
    float* scl   = (float*)(ws + (size_t)36 * 1024 * 1024 + 16 * 1024); // 16 KB

    hipLaunchKernelGGL(prep_kernel, dim3(OC_N), dim3(256), 0, stream,
                       w, x, ow, idx, wsgn, xq, xo, wcorr, scl, sx, n_out);
    hipLaunchKernelGGL(gemm_kernel, dim3(256), dim3(512), 0, stream,
                       xq, wsgn, xo, wcorr, sx, scl, bias, out);
}